// Round 1
// baseline (205.003 us; speedup 1.0000x reference)
//
#include <hip/hip_runtime.h>
#include <stdint.h>

#define Hdim 112
#define Wdim 112
#define CIN  128
#define COUT 128
#define NB   32
#define HW   (Hdim*Wdim)   // 12544

// ws layout:
//   Wp  : uint4[COUT*9]   @ 0        (18432 B)  packed weight sign bits
//   cw  : int [COUT*9]    @ 18432    (4608 B)   128 - 2*popc(w_tap)
//   pkx : uint4[NB*HW]    @ 23040    (6.4 MB)   packed activation sign bits

__global__ void pack_w_kernel(const float* __restrict__ W,
                              uint4* __restrict__ Wp, int* __restrict__ cw) {
    int t = blockIdx.x * blockDim.x + threadIdx.x;
    if (t >= COUT * 9) return;
    int co = t / 9, tap = t % 9;
    uint32_t m0 = 0, m1 = 0, m2 = 0, m3 = 0;
    const float* wp = W + (size_t)co * CIN * 9 + tap;
    #pragma unroll
    for (int c = 0; c < CIN; c++) {
        uint32_t bit = (__float_as_uint(wp[(size_t)c * 9]) >> 31);
        if (c < 32)       m0 |= bit << (c & 31);
        else if (c < 64)  m1 |= bit << (c & 31);
        else if (c < 96)  m2 |= bit << (c & 31);
        else              m3 |= bit << (c & 31);
    }
    Wp[t] = make_uint4(m0, m1, m2, m3);
    cw[t] = CIN - 2 * (__popc(m0) + __popc(m1) + __popc(m2) + __popc(m3));
}

// each thread packs 2 consecutive pixels across all 128 channels
__global__ __launch_bounds__(256) void pack_x_kernel(const float* __restrict__ x,
                                                     uint4* __restrict__ pkx) {
    int gid = blockIdx.x * blockDim.x + threadIdx.x;   // 0..200703
    int n = gid / (HW / 2);
    int p = (gid - n * (HW / 2)) * 2;
    const float* xp = x + (size_t)n * CIN * HW + p;
    uint32_t a0=0,a1=0,a2=0,a3=0, b0=0,b1=0,b2=0,b3=0;
    #pragma unroll
    for (int c = 0; c < CIN; c++) {
        float2 v = *reinterpret_cast<const float2*>(xp + (size_t)c * HW);
        uint32_t ba = __float_as_uint(v.x) >> 31;
        uint32_t bb = __float_as_uint(v.y) >> 31;
        if (c < 32)      { a0 |= ba << (c & 31); b0 |= bb << (c & 31); }
        else if (c < 64) { a1 |= ba << (c & 31); b1 |= bb << (c & 31); }
        else if (c < 96) { a2 |= ba << (c & 31); b2 |= bb << (c & 31); }
        else             { a3 |= ba << (c & 31); b3 |= bb << (c & 31); }
    }
    pkx[(size_t)n * HW + p]     = make_uint4(a0, a1, a2, a3);
    pkx[(size_t)n * HW + p + 1] = make_uint4(b0, b1, b2, b3);
}

// main conv: block = 16x16 pixel tile, loops 32 c_out; OOB taps loaded as 0 bits
__global__ __launch_bounds__(256) void binconv_kernel(
    const uint4* __restrict__ pkx, const uint4* __restrict__ Wp,
    const float* __restrict__ bias, float* __restrict__ out) {
    int tx = threadIdx.x & 15;
    int ty = threadIdx.x >> 4;
    int w = blockIdx.x * 16 + tx;
    int h = blockIdx.y * 16 + ty;
    int bz = blockIdx.z;
    int n   = bz >> 2;
    int co0 = (bz & 3) * 32;

    const uint4* px = pkx + (size_t)n * HW;
    uint4 xw[3][3];
    #pragma unroll
    for (int dy = 0; dy < 3; dy++) {
        #pragma unroll
        for (int dx = 0; dx < 3; dx++) {
            int hh = h + dy - 1, ww = w + dx - 1;
            bool valid = (hh >= 0) & (hh < Hdim) & (ww >= 0) & (ww < Wdim);
            int hc = min(max(hh, 0), Hdim - 1);
            int wc = min(max(ww, 0), Wdim - 1);
            uint4 v = px[hc * Wdim + wc];
            uint4 z = make_uint4(0u, 0u, 0u, 0u);
            xw[dy][dx] = valid ? v : z;
        }
    }

    float* outp = out + ((size_t)(n * COUT + co0) * HW) + h * Wdim + w;
    const uint4* wv = Wp + co0 * 9;
    const float* bp = bias + co0;
    #pragma unroll 2
    for (int co = 0; co < 32; co++) {
        int P0 = 0, P1 = 0, P2 = 0, P3 = 0;
        #pragma unroll
        for (int t = 0; t < 9; t++) {
            uint4 wt = wv[t];
            uint4 a  = xw[t / 3][t % 3];
            P0 += __popc(a.x ^ wt.x);
            P1 += __popc(a.y ^ wt.y);
            P2 += __popc(a.z ^ wt.z);
            P3 += __popc(a.w ^ wt.w);
        }
        float fb = 1152.0f + bp[co];
        *outp = fmaf(-2.0f, (float)(P0 + P1 + P2 + P3), fb);
        outp += HW;
        wv += 9;
    }
}

// subtract the spurious zero-pad contribution on the 444 border pixels/image
__global__ void border_fix_kernel(const int* __restrict__ cw, float* __restrict__ out) {
    const int BP = 444;
    int t = blockIdx.x * blockDim.x + threadIdx.x;
    int total = NB * COUT * BP;
    if (t >= total) return;
    int bp = t % BP;
    int rc = t / BP;
    int co = rc % COUT;
    int n  = rc / COUT;
    int h, w;
    if (bp < 112)      { h = 0;   w = bp; }
    else if (bp < 224) { h = 111; w = bp - 112; }
    else { int r = bp - 224; h = (r >> 1) + 1; w = (r & 1) ? 111 : 0; }
    const int* c9 = cw + co * 9;
    int corr = 0;
    #pragma unroll
    for (int ky = 0; ky < 3; ky++) {
        #pragma unroll
        for (int kx = 0; kx < 3; kx++) {
            int hh = h + ky - 1, ww = w + kx - 1;
            if ((hh < 0) | (hh >= Hdim) | (ww < 0) | (ww >= Wdim))
                corr += c9[ky * 3 + kx];
        }
    }
    size_t idx = ((size_t)(n * COUT + co) * HW) + (size_t)h * Wdim + w;
    out[idx] -= (float)corr;
}

extern "C" void kernel_launch(void* const* d_in, const int* in_sizes, int n_in,
                              void* d_out, int out_size, void* d_ws, size_t ws_size,
                              hipStream_t stream) {
    const float* x = (const float*)d_in[0];
    const float* W = (const float*)d_in[1];
    const float* b = (const float*)d_in[2];
    float* out = (float*)d_out;
    char* ws = (char*)d_ws;
    uint4* Wp  = (uint4*)ws;
    int*   cw  = (int*)(ws + 18432);
    uint4* pkx = (uint4*)(ws + 23040);

    pack_w_kernel<<<dim3((COUT * 9 + 255) / 256), dim3(256), 0, stream>>>(W, Wp, cw);
    pack_x_kernel<<<dim3(NB * HW / 2 / 256), dim3(256), 0, stream>>>(x, pkx);
    binconv_kernel<<<dim3(7, 7, NB * 4), dim3(256), 0, stream>>>(pkx, Wp, b, out);
    border_fix_kernel<<<dim3((NB * COUT * 444 + 255) / 256), dim3(256), 0, stream>>>(cw, out);
}